// Round 9
// baseline (528.266 us; speedup 1.0000x reference)
//
#include <hip/hip_runtime.h>

constexpr int N_NODES = 100000;
constexpr int N_EDGES = 1600000;
constexpr int D = 32;

// ---- primary path params ----
constexpr int NPB = 256;                          // nodes per bucket
constexpr int NBUK = (N_NODES + NPB - 1) / NPB;   // 391
constexpr int NCHUNK = 512;                       // sequential edge chunks
constexpr int EPC = N_EDGES / NCHUNK;             // 3125 edges per chunk (exact)

__device__ inline unsigned short f2bf(float f) {
    unsigned u = __float_as_uint(f);
    u += 0x7FFFu + ((u >> 16) & 1u);              // round-to-nearest-even
    return (unsigned short)(u >> 16);
}
__device__ inline float bf2f(unsigned short h) {
    return __uint_as_float(((unsigned)h) << 16);
}

// P0: node f32 -> bf16 rows (64 B/row).
__global__ __launch_bounds__(256) void p_conv(const float4* __restrict__ in4,
                                              ushort4* __restrict__ out4) {
    int i = blockIdx.x * 256 + threadIdx.x;       // 800000 exact
    float4 v = in4[i];
    out4[i] = make_ushort4(f2bf(v.x), f2bf(v.y), f2bf(v.z), f2bf(v.w));
}

// P1: per-chunk LDS histogram over 391 buckets -> bgcnt[b][k] (bucket-major).
__global__ __launch_bounds__(256) void p_hist(const int* __restrict__ dst,
                                              int* __restrict__ bgcnt) {
    __shared__ int cnt_s[NBUK];
    const int k = blockIdx.x, t = threadIdx.x;
    for (int i = t; i < NBUK; i += 256) cnt_s[i] = 0;
    __syncthreads();
    const int e0 = k * EPC;
    for (int i = t; i < EPC; i += 256) atomicAdd(&cnt_s[dst[e0 + i] >> 8], 1);
    __syncthreads();
    for (int b = t; b < NBUK; b += 256) bgcnt[b * NCHUNK + k] = cnt_s[b];
}

// P2a: per-bucket totals (one block of 64 lanes per bucket, sequential row read).
__global__ __launch_bounds__(64) void p_tot(const int* __restrict__ bgcnt,
                                            int* __restrict__ tot) {
    const int b = blockIdx.x, l = threadIdx.x;
    int s = 0;
    for (int k = l; k < NCHUNK; k += 64) s += bgcnt[b * NCHUNK + k];
    #pragma unroll
    for (int d = 32; d >= 1; d >>= 1) s += __shfl_down(s, d, 64);
    if (l == 0) tot[b] = s;
}

// P2b: exclusive scan of 391 totals -> boff (+ sentinel).
__global__ __launch_bounds__(512) void p_scan(const int* __restrict__ tot,
                                              int* __restrict__ boff) {
    __shared__ int part[512];
    const int t = threadIdx.x;
    int v = (t < NBUK) ? tot[t] : 0;
    part[t] = v;
    __syncthreads();
    for (int d = 1; d < 512; d <<= 1) {
        int u = (t >= d) ? part[t - d] : 0;
        __syncthreads();
        part[t] += u;
        __syncthreads();
    }
    if (t < NBUK) boff[t] = part[t] - v;
    if (t == 0) boff[NBUK] = N_EDGES;
}

// P2c: per-(bucket,chunk) stripe starts: gstart[b][k] = boff[b] + prefix.
__global__ __launch_bounds__(64) void p_gstart(const int* __restrict__ bgcnt,
                                               const int* __restrict__ boff,
                                               int* __restrict__ gstart) {
    const int b = blockIdx.x, l = threadIdx.x;
    int carry = boff[b];
    for (int k0 = 0; k0 < NCHUNK; k0 += 64) {
        const int v = bgcnt[b * NCHUNK + k0 + l];
        int incl = v;
        #pragma unroll
        for (int d = 1; d < 64; d <<= 1) {
            int u = __shfl_up(incl, d, 64);
            if (l >= d) incl += u;
        }
        gstart[b * NCHUNK + k0 + l] = carry + incl - v;
        carry += __shfl(incl, 63, 64);    // wave-uniform running total
    }
}

// P3: stream edges SEQUENTIALLY (8 lanes/edge); claim stripe slot via LDS
// cursor; write 64B line-aligned bf16 msg row (single owner) + 4B local id.
__global__ __launch_bounds__(512) void p_mat(
    const float4* __restrict__ edge4, const ushort4* __restrict__ nodeb4,
    const int* __restrict__ src, const int* __restrict__ dst,
    const int* __restrict__ gstart, ushort4* __restrict__ msg4,
    int* __restrict__ loc)
{
    __shared__ int cur_s[NBUK];
    const int k = blockIdx.x, t = threadIdx.x;
    for (int b = t; b < NBUK; b += 512) cur_s[b] = gstart[b * NCHUNK + k];
    __syncthreads();

    const int l = t & 63;
    const int wv = t >> 6;                // 0..7
    const int sub = l >> 3;               // edge slot in wave (0..7)
    const int q = l & 7;                  // row piece (float4)
    const int e0 = k * EPC;

    for (int eg = wv * 8 + sub; ; eg += 64) {
        const bool act = (eg < EPC);
        if (__builtin_amdgcn_ballot_w64(act) == 0ull) break;
        const int e = e0 + eg;
        int p = 0, d_ = 0, s_ = 0;
        if (act) {
            s_ = src[e];                  // same addr across the 8-lane group
            if (q == 0) {
                d_ = dst[e];
                p = atomicAdd(&cur_s[d_ >> 8], 1);
            }
        }
        p = __shfl(p, l & ~7, 64);        // broadcast slot within group
        if (act) {
            const float4 ev = edge4[(long long)e * 8 + q];      // sequential
            const ushort4 nb = nodeb4[(long long)s_ * 8 + q];   // 64B random, L2-ish
            ushort4 m;
            m.x = f2bf(fmaxf(ev.x + bf2f(nb.x), 0.0f));
            m.y = f2bf(fmaxf(ev.y + bf2f(nb.y), 0.0f));
            m.z = f2bf(fmaxf(ev.z + bf2f(nb.z), 0.0f));
            m.w = f2bf(fmaxf(ev.w + bf2f(nb.w), 0.0f));
            msg4[(long long)p * 8 + q] = m;                     // 64B single-owner
            if (q == 0) loc[p] = d_ & 255;
        }
    }
}

// P4: one block per bucket: sequential read of the bucket's contiguous msg
// region; LDS-atomic accumulate into padded acc[256][33]; fused eps+linear.
__global__ __launch_bounds__(512) void p_reduce(
    const float* __restrict__ node, const ushort4* __restrict__ msg4,
    const int* __restrict__ loc, const int* __restrict__ boff,
    const float* __restrict__ W, const float* __restrict__ bvec,
    const float* __restrict__ eps, float* __restrict__ out)
{
    __shared__ float Ws[D][D + 1];
    __shared__ float bs[D];
    __shared__ float acc[NPB][D + 1];     // +1 pad: LDS-atomic banks spread
    const int t = threadIdx.x;
    const int b = blockIdx.x;
    for (int i = t; i < D * D; i += 512) Ws[i >> 5][i & 31] = W[i];
    if (t < D) bs[t] = bvec[t];
    for (int i = t; i < NPB * (D + 1); i += 512) (&acc[0][0])[i] = 0.0f;
    __syncthreads();

    const int start = boff[b];
    const int tot = boff[b + 1] - start;
    const int l = t & 63;
    const int wv = t >> 6;
    const int sub = l >> 3;
    const int q = l & 7;

    for (int r0 = wv * 8 + sub; ; r0 += 64) {
        const bool act = (r0 < tot);
        if (__builtin_amdgcn_ballot_w64(act) == 0ull) break;
        int lv = 0;
        if (act && q == 0) lv = loc[start + r0];
        lv = __shfl(lv, l & ~7, 64);
        if (act) {
            const ushort4 mv = msg4[(long long)(start + r0) * 8 + q];  // sequential
            atomicAdd(&acc[lv][q * 4 + 0], bf2f(mv.x));
            atomicAdd(&acc[lv][q * 4 + 1], bf2f(mv.y));
            atomicAdd(&acc[lv][q * 4 + 2], bf2f(mv.z));
            atomicAdd(&acc[lv][q * 4 + 3], bf2f(mv.w));
        }
    }
    __syncthreads();

    const float scale = 1.0f + eps[0];
    const int o = t & 31;
    const int grp = t >> 5;               // 0..15
    #pragma unroll
    for (int it = 0; it < 16; ++it) {
        const int g = it * 16 + grp;      // local node 0..255
        const int gn = b * NPB + g;
        if (gn < N_NODES) {               // uniform within 32-lane group
            const float h = scale * node[(long long)gn * D + o] + acc[g][o];
            float r = bs[o];
            #pragma unroll
            for (int kk = 0; kk < D; ++kk) r += __shfl(h, kk, 32) * Ws[o][kk];
            out[(long long)gn * D + o] = r;
        }
    }
}

// ---------------- fallback (R8 pipeline, ~8 MB) ----------------
constexpr int F_NPB = 256;
constexpr int F_NBUK = (N_NODES + F_NPB - 1) / F_NPB;
constexpr int F_NCHUNK = 128;
constexpr int F_EPC = N_EDGES / F_NCHUNK;
constexpr int F_MAXPT = 32;

__global__ __launch_bounds__(256) void f_hist(const int4* __restrict__ dst4,
                                              int* __restrict__ bgcnt) {
    __shared__ int cnt_s[512];
    const int k = blockIdx.x, t = threadIdx.x;
    cnt_s[t] = 0; cnt_s[t + 256] = 0;
    __syncthreads();
    const int base4 = k * (F_EPC / 4);
    for (int i = t; i < F_EPC / 4; i += 256) {
        int4 d = dst4[base4 + i];
        atomicAdd(&cnt_s[d.x >> 8], 1);
        atomicAdd(&cnt_s[d.y >> 8], 1);
        atomicAdd(&cnt_s[d.z >> 8], 1);
        atomicAdd(&cnt_s[d.w >> 8], 1);
    }
    __syncthreads();
    for (int b = t; b < F_NBUK; b += 256) bgcnt[k * F_NBUK + b] = cnt_s[b];
}

__global__ __launch_bounds__(512) void f_offsets(const int* __restrict__ bgcnt,
                                                 int* __restrict__ gstart,
                                                 int* __restrict__ boff) {
    __shared__ int part[512];
    const int t = threadIdx.x;
    int tot = 0;
    if (t < F_NBUK)
        for (int k = 0; k < F_NCHUNK; ++k) tot += bgcnt[k * F_NBUK + t];
    part[t] = tot;
    __syncthreads();
    for (int d = 1; d < 512; d <<= 1) {
        int u = (t >= d) ? part[t - d] : 0;
        __syncthreads();
        part[t] += u;
        __syncthreads();
    }
    const int my_off = part[t] - tot;
    if (t < F_NBUK) {
        boff[t] = my_off;
        int run = my_off;
        for (int k = 0; k < F_NCHUNK; ++k) {
            gstart[k * F_NBUK + t] = run;
            run += bgcnt[k * F_NBUK + t];
        }
    }
}

__global__ __launch_bounds__(256) void f_scatter(const int4* __restrict__ dst4,
                                                 const int* __restrict__ gstart,
                                                 int* __restrict__ records) {
    __shared__ int cur_s[512];
    const int k = blockIdx.x, t = threadIdx.x;
    for (int b = t; b < 512; b += 256)
        cur_s[b] = (b < F_NBUK) ? gstart[k * F_NBUK + b] : 0;
    __syncthreads();
    const int base4 = k * (F_EPC / 4);
    for (int i = t; i < F_EPC / 4; i += 256) {
        int4 d = dst4[base4 + i];
        const int e = (base4 + i) * 4;
        int p;
        p = atomicAdd(&cur_s[d.x >> 8], 1); records[p] = e       | ((d.x & 255) << 21);
        p = atomicAdd(&cur_s[d.y >> 8], 1); records[p] = (e + 1) | ((d.y & 255) << 21);
        p = atomicAdd(&cur_s[d.z >> 8], 1); records[p] = (e + 2) | ((d.z & 255) << 21);
        p = atomicAdd(&cur_s[d.w >> 8], 1); records[p] = (e + 3) | ((d.w & 255) << 21);
    }
}

__global__ __launch_bounds__(256) void f_finalize(int* __restrict__ records,
                                                  const int* __restrict__ boff,
                                                  int2* __restrict__ offcnt) {
    __shared__ int cnt_s[F_NPB];
    __shared__ int cur_s[F_NPB];
    __shared__ int wsum_s[4];
    const int b = blockIdx.x, t = threadIdx.x;
    const int s0 = boff[b];
    const int tot = ((b + 1 < F_NBUK) ? boff[b + 1] : N_EDGES) - s0;
    cnt_s[t] = 0;
    __syncthreads();
    int held[F_MAXPT];
    #pragma unroll
    for (int r = 0; r < F_MAXPT; ++r) {
        const int i = t + r * 256;
        held[r] = (i < tot) ? records[s0 + i] : -1;
        if (held[r] >= 0) atomicAdd(&cnt_s[held[r] >> 21], 1);
    }
    __syncthreads();
    const int lane = t & 63, w = t >> 6;
    const int v = cnt_s[t];
    int incl = v;
    #pragma unroll
    for (int dd = 1; dd < 64; dd <<= 1) {
        int u = __shfl_up(incl, dd, 64);
        if (lane >= dd) incl += u;
    }
    if (lane == 63) wsum_s[w] = incl;
    __syncthreads();
    int wo = 0;
    for (int ww = 0; ww < w; ++ww) wo += wsum_s[ww];
    const int excl = s0 + wo + incl - v;
    cur_s[t] = excl;
    const int gn = b * F_NPB + t;
    if (gn < N_NODES) offcnt[gn] = make_int2(excl, v);
    __syncthreads();
    #pragma unroll
    for (int r = 0; r < F_MAXPT; ++r) {
        if (held[r] >= 0) {
            const int pos = atomicAdd(&cur_s[held[r] >> 21], 1);
            records[pos] = held[r] & 0x1FFFFF;
        }
    }
}

__global__ __launch_bounds__(256) void f_gather(
    const float* __restrict__ node, const float* __restrict__ edge,
    const int* __restrict__ src, const int2* __restrict__ offcnt,
    const int* __restrict__ eid,
    const float* __restrict__ W, const float* __restrict__ bvec,
    const float* __restrict__ eps, float* __restrict__ out)
{
    __shared__ float Ws[D][D + 1];
    __shared__ float bs[D];
    const int t = threadIdx.x;
    for (int i = t; i < D * D; i += 256) Ws[i >> 5][i & 31] = W[i];
    if (t < D) bs[t] = bvec[t];
    __syncthreads();
    const int g = t >> 5;
    const int o = t & 31;
    const int nodeid = blockIdx.x * 8 + g;
    if (nodeid >= N_NODES) return;
    const int2 oc = offcnt[nodeid];
    const int start = oc.x;
    const int n = oc.y;
    float acc = 0.0f;
    for (int c = 0; c < n; c += 32) {
        const int m = min(32, n - c);
        int e_l = 0, s_l = 0;
        if (o < m) { e_l = eid[start + c + o]; s_l = src[e_l]; }
        for (int j = 0; j < m; j += 16) {
            float ev[16], nv[16];
            #pragma unroll
            for (int u = 0; u < 16; ++u) {
                const int jj = j + u;
                const int ls = (jj < m) ? jj : (m - 1);
                const int e = __shfl(e_l, ls, 32);
                const int s = __shfl(s_l, ls, 32);
                ev[u] = edge[(long long)e * D + o];
                nv[u] = node[(long long)s * D + o];
            }
            #pragma unroll
            for (int u = 0; u < 16; ++u)
                if (j + u < m) acc += fmaxf(ev[u] + nv[u], 0.0f);
        }
    }
    const float scale = 1.0f + eps[0];
    const float h = scale * node[(long long)nodeid * D + o] + acc;
    float r = bs[o];
    #pragma unroll
    for (int kk = 0; kk < D; ++kk) r += __shfl(h, kk, 32) * Ws[o][kk];
    out[(long long)nodeid * D + o] = r;
}

// ---------------------------------------------------------------------

extern "C" void kernel_launch(void* const* d_in, const int* in_sizes, int n_in,
                              void* d_out, int out_size, void* d_ws, size_t ws_size,
                              hipStream_t stream) {
    const float* node = (const float*)d_in[0];
    const float* edge = (const float*)d_in[1];
    const int*   src  = (const int*)d_in[2];
    const int*   dst  = (const int*)d_in[3];
    const float* W    = (const float*)d_in[4];
    const float* b    = (const float*)d_in[5];
    const float* eps  = (const float*)d_in[6];
    float* out = (float*)d_out;

    // Primary layout: msg bf16[E*D] | nodeb bf16[N*D] | loc[E] |
    //                 bgcnt[NBUK*NCHUNK] | gstart[NBUK*NCHUNK] |
    //                 boff[NBUK+1] | tot[NBUK]   (~118 MB)
    const size_t need = (size_t)N_EDGES * D * 2 + (size_t)N_NODES * D * 2
                      + (size_t)N_EDGES * 4 + (size_t)NBUK * NCHUNK * 8
                      + (size_t)(2 * NBUK + 2) * 4 + 1024;

    if (ws_size >= need) {
        unsigned short* msg   = (unsigned short*)d_ws;
        unsigned short* nodeb = msg + (size_t)N_EDGES * D;
        int* loc    = (int*)(nodeb + (size_t)N_NODES * D);
        int* bgcnt  = loc + N_EDGES;
        int* gstart = bgcnt + (size_t)NBUK * NCHUNK;
        int* boff   = gstart + (size_t)NBUK * NCHUNK;
        int* tot    = boff + NBUK + 1;

        p_conv<<<(N_NODES * D / 4) / 256, 256, 0, stream>>>(
            (const float4*)node, (ushort4*)nodeb);
        p_hist<<<NCHUNK, 256, 0, stream>>>(dst, bgcnt);
        p_tot<<<NBUK, 64, 0, stream>>>(bgcnt, tot);
        p_scan<<<1, 512, 0, stream>>>(tot, boff);
        p_gstart<<<NBUK, 64, 0, stream>>>(bgcnt, boff, gstart);
        p_mat<<<NCHUNK, 512, 0, stream>>>((const float4*)edge,
                                          (const ushort4*)nodeb,
                                          src, dst, gstart, (ushort4*)msg, loc);
        p_reduce<<<NBUK, 512, 0, stream>>>(node, (const ushort4*)msg, loc, boff,
                                           W, b, eps, out);
    } else {
        int*  records = (int*)d_ws;
        int*  bgcnt   = records + N_EDGES;
        int*  gstart  = bgcnt + F_NCHUNK * F_NBUK;
        int*  boff    = gstart + F_NCHUNK * F_NBUK;
        int2* offcnt  = (int2*)(boff + F_NBUK);

        f_hist<<<F_NCHUNK, 256, 0, stream>>>((const int4*)dst, bgcnt);
        f_offsets<<<1, 512, 0, stream>>>(bgcnt, gstart, boff);
        f_scatter<<<F_NCHUNK, 256, 0, stream>>>((const int4*)dst, gstart, records);
        f_finalize<<<F_NBUK, 256, 0, stream>>>(records, boff, offcnt);
        f_gather<<<(N_NODES + 7) / 8, 256, 0, stream>>>(node, edge, src, offcnt,
                                                        records, W, b, eps, out);
    }
}

// Round 10
// 143.107 us; speedup vs baseline: 3.6914x; 3.6914x over previous
//
#include <hip/hip_runtime.h>

constexpr int N_NODES = 100000;
constexpr int N_EDGES = 1600000;
constexpr int D = 32;
constexpr int NPB = 256;                            // nodes per bucket
constexpr int NBUK = (N_NODES + NPB - 1) / NPB;     // 391 buckets
constexpr int NCHUNK = 128;                         // edge chunks
constexpr int EPC = N_EDGES / NCHUNK;               // 12500 (exact)
constexpr int MAXPT = 32;                           // 32*256=8192 >= 4096 + many sigma

__device__ inline unsigned short f2bf(float f) {
    unsigned u = __float_as_uint(f);
    u += 0x7FFFu + ((u >> 16) & 1u);                // round-to-nearest-even
    return (unsigned short)(u >> 16);
}
__device__ inline float bf2f(unsigned short h) {
    return __uint_as_float(((unsigned)h) << 16);
}

// P0: node f32 -> bf16 table (64 B/row; ~6.4 MB, mostly L2-resident).
__global__ __launch_bounds__(256) void conv_kernel(const float4* __restrict__ in4,
                                                   ushort4* __restrict__ out4) {
    int i = blockIdx.x * 256 + threadIdx.x;         // 800000 exact
    float4 v = in4[i];
    out4[i] = make_ushort4(f2bf(v.x), f2bf(v.y), f2bf(v.z), f2bf(v.w));
}

// K1: per-chunk LDS histogram over buckets -> bgcnt[chunk][bucket].
__global__ __launch_bounds__(256) void hist_kernel(const int4* __restrict__ dst4,
                                                   int* __restrict__ bgcnt) {
    __shared__ int cnt_s[512];
    const int k = blockIdx.x, t = threadIdx.x;
    cnt_s[t] = 0; cnt_s[t + 256] = 0;
    __syncthreads();
    const int base4 = k * (EPC / 4);
    for (int i = t; i < EPC / 4; i += 256) {
        int4 d = dst4[base4 + i];
        atomicAdd(&cnt_s[d.x >> 8], 1);
        atomicAdd(&cnt_s[d.y >> 8], 1);
        atomicAdd(&cnt_s[d.z >> 8], 1);
        atomicAdd(&cnt_s[d.w >> 8], 1);
    }
    __syncthreads();
    for (int b = t; b < NBUK; b += 256) bgcnt[k * NBUK + b] = cnt_s[b];
}

// K2: bucket totals -> exclusive bucket scan (boff) + per-(chunk,bucket)
// stripe starts (gstart). Coalesced across the 391 buckets.
__global__ __launch_bounds__(512) void offsets_kernel(const int* __restrict__ bgcnt,
                                                      int* __restrict__ gstart,
                                                      int* __restrict__ boff) {
    __shared__ int part[512];
    const int t = threadIdx.x;
    int tot = 0;
    if (t < NBUK)
        for (int k = 0; k < NCHUNK; ++k) tot += bgcnt[k * NBUK + t];
    part[t] = tot;
    __syncthreads();
    for (int d = 1; d < 512; d <<= 1) {
        int u = (t >= d) ? part[t - d] : 0;
        __syncthreads();
        part[t] += u;
        __syncthreads();
    }
    const int my_off = part[t] - tot;
    if (t < NBUK) {
        boff[t] = my_off;
        int run = my_off;
        for (int k = 0; k < NCHUNK; ++k) {
            gstart[k * NBUK + t] = run;
            run += bgcnt[k * NBUK + t];
        }
    }
}

// K3: scatter packed records (e | local<<21) into bucket-major order.
// Each (bucket,chunk) stripe is contiguous, written by exactly one block.
__global__ __launch_bounds__(256) void scatter_kernel(const int4* __restrict__ dst4,
                                                      const int* __restrict__ gstart,
                                                      int* __restrict__ records) {
    __shared__ int cur_s[512];
    const int k = blockIdx.x, t = threadIdx.x;
    for (int b = t; b < 512; b += 256)
        cur_s[b] = (b < NBUK) ? gstart[k * NBUK + b] : 0;
    __syncthreads();
    const int base4 = k * (EPC / 4);
    for (int i = t; i < EPC / 4; i += 256) {
        int4 d = dst4[base4 + i];
        const int e = (base4 + i) * 4;
        int p;
        p = atomicAdd(&cur_s[d.x >> 8], 1); records[p] = e       | ((d.x & 255) << 21);
        p = atomicAdd(&cur_s[d.y >> 8], 1); records[p] = (e + 1) | ((d.y & 255) << 21);
        p = atomicAdd(&cur_s[d.z >> 8], 1); records[p] = (e + 2) | ((d.z & 255) << 21);
        p = atomicAdd(&cur_s[d.w >> 8], 1); records[p] = (e + 3) | ((d.w & 255) << 21);
    }
}

// K4: one block per bucket. Register-buffer the records, LDS hist+scan of the
// 256 local nodes -> offcnt, then emit node-sorted CSR as eidsrc = (e, src[e])
// (src gather is L2-hot and happens HERE, off the gather's critical path).
__global__ __launch_bounds__(256) void finalize_kernel(const int* __restrict__ records,
                                                       const int* __restrict__ src,
                                                       const int* __restrict__ boff,
                                                       int2* __restrict__ offcnt,
                                                       int2* __restrict__ eidsrc) {
    __shared__ int cnt_s[NPB];
    __shared__ int cur_s[NPB];
    __shared__ int wsum_s[4];
    const int b = blockIdx.x, t = threadIdx.x;
    const int s0 = boff[b];
    const int tot = ((b + 1 < NBUK) ? boff[b + 1] : N_EDGES) - s0;
    cnt_s[t] = 0;
    __syncthreads();

    int held[MAXPT];
    #pragma unroll
    for (int r = 0; r < MAXPT; ++r) {
        const int i = t + r * 256;
        held[r] = (i < tot) ? records[s0 + i] : -1;
        if (held[r] >= 0) atomicAdd(&cnt_s[held[r] >> 21], 1);
    }
    __syncthreads();

    const int lane = t & 63, w = t >> 6;
    const int v = cnt_s[t];
    int incl = v;
    #pragma unroll
    for (int dd = 1; dd < 64; dd <<= 1) {
        int u = __shfl_up(incl, dd, 64);
        if (lane >= dd) incl += u;
    }
    if (lane == 63) wsum_s[w] = incl;
    __syncthreads();
    int wo = 0;
    for (int ww = 0; ww < w; ++ww) wo += wsum_s[ww];
    const int excl = s0 + wo + incl - v;
    cur_s[t] = excl;
    const int gn = b * NPB + t;
    if (gn < N_NODES) offcnt[gn] = make_int2(excl, v);
    __syncthreads();

    #pragma unroll
    for (int r = 0; r < MAXPT; ++r) {
        if (held[r] >= 0) {
            const int e = held[r] & 0x1FFFFF;
            const int pos = atomicAdd(&cur_s[held[r] >> 21], 1);
            eidsrc[pos] = make_int2(e, src[e]);     // src gather: L2-hot, hidden
        }
    }
}

// K5: per-node gather-sum + eps-update + 32x32 linear. 32 lanes per node,
// single coalesced int2 prefetch (e,s) per 32 edges, 16-wide batches.
// Edge rows f32 (random, L3); node rows bf16 (random, mostly L2).
__global__ __launch_bounds__(256) void gather_node_kernel(
    const float* __restrict__ node, const unsigned short* __restrict__ nodeb,
    const float* __restrict__ edge, const int2* __restrict__ eidsrc,
    const int2* __restrict__ offcnt,
    const float* __restrict__ W, const float* __restrict__ bvec,
    const float* __restrict__ eps, float* __restrict__ out)
{
    __shared__ float Ws[D][D + 1];
    __shared__ float bs[D];
    const int t = threadIdx.x;
    for (int i = t; i < D * D; i += 256) Ws[i >> 5][i & 31] = W[i];
    if (t < D) bs[t] = bvec[t];
    __syncthreads();

    const int g = t >> 5;
    const int o = t & 31;
    const int nodeid = blockIdx.x * 8 + g;          // 12500*8 exact

    const int2 oc = offcnt[nodeid];
    const int start = oc.x;
    const int n = oc.y;
    float acc = 0.0f;

    for (int c = 0; c < n; c += 32) {
        const int m = min(32, n - c);
        int e_l = 0, s_l = 0;
        if (o < m) {
            const int2 es = eidsrc[start + c + o];  // ONE coalesced dependent load
            e_l = es.x; s_l = es.y;
        }
        for (int j = 0; j < m; j += 16) {
            float ev[16], nv[16];
            #pragma unroll
            for (int u = 0; u < 16; ++u) {
                const int jj = j + u;
                const int ls = (jj < m) ? jj : (m - 1);   // clamp: dup row, L1-hit
                const int e = __shfl(e_l, ls, 32);
                const int s = __shfl(s_l, ls, 32);
                ev[u] = edge[(long long)e * D + o];               // 128B random
                nv[u] = bf2f(nodeb[(long long)s * D + o]);        // 64B random, L2
            }
            #pragma unroll
            for (int u = 0; u < 16; ++u)
                if (j + u < m) acc += fmaxf(ev[u] + nv[u], 0.0f);
        }
    }

    const float scale = 1.0f + eps[0];
    const float h = scale * node[(long long)nodeid * D + o] + acc;  // self term f32

    float r = bs[o];
    #pragma unroll
    for (int kk = 0; kk < D; ++kk) r += __shfl(h, kk, 32) * Ws[o][kk];
    out[(long long)nodeid * D + o] = r;
}

extern "C" void kernel_launch(void* const* d_in, const int* in_sizes, int n_in,
                              void* d_out, int out_size, void* d_ws, size_t ws_size,
                              hipStream_t stream) {
    const float* node = (const float*)d_in[0];
    const float* edge = (const float*)d_in[1];
    const int*   src  = (const int*)d_in[2];
    const int*   dst  = (const int*)d_in[3];
    const float* W    = (const float*)d_in[4];
    const float* b    = (const float*)d_in[5];
    const float* eps  = (const float*)d_in[6];
    float* out = (float*)d_out;

    // Workspace: eidsrc int2[E] | offcnt int2[N] | records[E] |
    //            bgcnt[NCHUNK*NBUK] | gstart[NCHUNK*NBUK] | boff[NBUK] |
    //            nodeb ushort[N*D]            (~27 MB total)
    int2* eidsrc = (int2*)d_ws;
    int2* offcnt = eidsrc + N_EDGES;
    int*  records = (int*)(offcnt + N_NODES);
    int*  bgcnt   = records + N_EDGES;
    int*  gstart  = bgcnt + NCHUNK * NBUK;
    int*  boff    = gstart + NCHUNK * NBUK;
    unsigned short* nodeb = (unsigned short*)(boff + NBUK);

    conv_kernel<<<(N_NODES * D / 4) / 256, 256, 0, stream>>>(
        (const float4*)node, (ushort4*)nodeb);
    hist_kernel<<<NCHUNK, 256, 0, stream>>>((const int4*)dst, bgcnt);
    offsets_kernel<<<1, 512, 0, stream>>>(bgcnt, gstart, boff);
    scatter_kernel<<<NCHUNK, 256, 0, stream>>>((const int4*)dst, gstart, records);
    finalize_kernel<<<NBUK, 256, 0, stream>>>(records, src, boff, offcnt, eidsrc);

    gather_node_kernel<<<N_NODES / 8, 256, 0, stream>>>(node, nodeb, edge, eidsrc,
                                                        offcnt, W, b, eps, out);
}